// Round 5
// baseline (52.009 us; speedup 1.0000x reference)
//
#include <hip/hip_runtime.h>
#include <hip/hip_cooperative_groups.h>
#include <math.h>

namespace cg = cooperative_groups;

#define BB 32
#define FF 6
#define NN 1024

// ===========================================================================
// Cooperative fused kernel: min phase -> grid.sync -> softmax phase.
// Runtime geometry: bpb = 1<<bshift blocks per batch (8 or 16),
// rpb = NN>>bshift rows per block. Block c: batch b = c>>bshift,
// sub = c & (bpb-1), rows i = sub + bpb*rloc.
// j-tile (6 features x 16 j per lane) register-resident for BOTH phases.
// ===========================================================================
__global__ __launch_bounds__(256, 2)
void k_fused(const float* __restrict__ emb, const float* __restrict__ alphap,
             const float* __restrict__ betap, float* __restrict__ partial,
             float* __restrict__ out, int bshift) {
    __shared__ float pm_lds[NN];
    __shared__ float e_lds[FF][128];   // max rpb = 128
    __shared__ float red[4];
    __shared__ float s_dmin;

    const int c = blockIdx.x;
    const int bpb = 1 << bshift;
    const int rpb = NN >> bshift;
    const int b = c >> bshift, sub = c & (bpb - 1);
    const int tid = threadIdx.x, wid = tid >> 6, lane = tid & 63;
    const float* e = emb + (size_t)b * FF * NN;
    const float a2 = 2.0f * alphap[0];

    // ---- setup (once per block): j-tile regs, pm LDS, row-feature LDS ----
    float4 q[FF][4];
    #pragma unroll
    for (int k = 0; k < 4; ++k) {
        const int j0 = k * 256 + lane * 4;
        #pragma unroll
        for (int f = 0; f < FF; ++f) q[f][k] = *(const float4*)(e + f * NN + j0);
    }
    {
        float4 m = *(const float4*)(e + 4 * NN + 4 * tid);
        float4 r;
        r.x = expf(a2 * logf(m.x));
        r.y = expf(a2 * logf(m.y));
        r.z = expf(a2 * logf(m.z));
        r.w = expf(a2 * logf(m.w));
        *(float4*)&pm_lds[4 * tid] = r;   // momentum^(2*alpha)
    }
    for (int t = tid; t < FF * rpb; t += 256) {
        const int f = t >> (10 - bshift);
        const int r = t & (rpb - 1);
        e_lds[f][r] = e[f * NN + sub + (r << bshift)];
    }
    __syncthreads();

    float pj[16];
    #pragma unroll
    for (int k = 0; k < 4; ++k) {
        float4 t4 = *(const float4*)&pm_lds[k * 256 + lane * 4];
        pj[k * 4 + 0] = t4.x; pj[k * 4 + 1] = t4.y;
        pj[k * 4 + 2] = t4.z; pj[k * 4 + 3] = t4.w;
    }

    // ---- phase 1: strict-upper-triangle min (kmin-balanced striding) ----
    float vmin = 3.4e38f;
    for (int rloc = wid; rloc < rpb; rloc += 4) {     // wave-uniform rloc
        const int i = sub + (rloc << bshift);
        float eif[FF];
        #pragma unroll
        for (int f = 0; f < FF; ++f) eif[f] = e_lds[f][rloc];  // broadcast
        const float pmi = pm_lds[i];
        const int kmin = i >> 8;
        #pragma unroll
        for (int k = 0; k < 4; ++k) {
            if (k >= kmin) {
                #pragma unroll
                for (int cc = 0; cc < 4; ++cc) {
                    float acc = 0.0f;
                    #pragma unroll
                    for (int f = 0; f < FF; ++f) {
                        float t = ((const float*)&q[f][k])[cc] - eif[f];
                        acc = fmaf(t, t, acc);   // no-cancellation form
                    }
                    float dd = acc * fminf(pmi, pj[k * 4 + cc]);
                    if (k == kmin) {
                        const int j = k * 256 + lane * 4 + cc;
                        vmin = (j > i) ? fminf(vmin, dd) : vmin;
                    } else {
                        vmin = fminf(vmin, dd);  // whole chunk is j > i
                    }
                }
            }
        }
    }
    #pragma unroll
    for (int o = 32; o >= 1; o >>= 1) vmin = fminf(vmin, __shfl_xor(vmin, o));
    if (lane == 0) red[wid] = vmin;
    __syncthreads();
    if (tid == 0)
        partial[c] = fminf(fminf(red[0], red[1]), fminf(red[2], red[3]));

    __threadfence();
    cg::this_grid().sync();
    __threadfence();

    // ---- batch dmin: reduce this batch's bpb partials ----
    if (wid == 0) {
        float v = partial[(b << bshift) + (lane & (bpb - 1))];
        #pragma unroll
        for (int o = 8; o >= 1; o >>= 1) v = fminf(v, __shfl_xor(v, o));
        if (lane == 0) s_dmin = v;
    }
    __syncthreads();
    const float beta = betap[0];
    const float s2 = beta * beta / s_dmin * 1.4426950408889634f;  // log2e folded

    // ---- phase 2: softmax rows, registers/LDS still warm ----
    for (int rloc = wid; rloc < rpb; rloc += 4) {
        const int i = sub + (rloc << bshift);
        float eif[FF];
        #pragma unroll
        for (int f = 0; f < FF; ++f) eif[f] = e_lds[f][rloc];
        const float pmi = pm_lds[i];

        float d[16];
        #pragma unroll
        for (int k = 0; k < 4; ++k)
            #pragma unroll
            for (int cc = 0; cc < 4; ++cc) {
                float acc = 0.0f;
                #pragma unroll
                for (int f = 0; f < FF; ++f) {
                    float t = ((const float*)&q[f][k])[cc] - eif[f];
                    acc = fmaf(t, t, acc);
                }
                float dd = acc * fminf(pmi, pj[k * 4 + cc]);
                const int j = k * 256 + lane * 4 + cc;
                d[k * 4 + cc] = (j == i) ? __builtin_inff() : dd;  // diag -> 0
            }

        float rmin = d[0];
        #pragma unroll
        for (int t = 1; t < 16; ++t) rmin = fminf(rmin, d[t]);
        #pragma unroll
        for (int o = 32; o >= 1; o >>= 1) rmin = fminf(rmin, __shfl_xor(rmin, o));

        float sum = 0.0f;
        #pragma unroll
        for (int t = 0; t < 16; ++t) {
            float p = __builtin_amdgcn_exp2f(-s2 * (d[t] - rmin));
            d[t] = p;
            sum += p;
        }
        #pragma unroll
        for (int o = 32; o >= 1; o >>= 1) sum += __shfl_xor(sum, o);
        const float inv = 1.0f / sum;

        float* op = out + ((size_t)b * NN + (size_t)i) * NN;
        #pragma unroll
        for (int k = 0; k < 4; ++k) {
            const int j0 = k * 256 + lane * 4;
            float4 w;
            w.x = d[k * 4 + 0] * inv;
            w.y = d[k * 4 + 1] * inv;
            w.z = d[k * 4 + 2] * inv;
            w.w = d[k * 4 + 3] * inv;
            *(float4*)&op[j0] = w;
        }
    }
}

// ===========================================================================
// Fallback path (proven round-3 kernels, 51.9 us) — used only if the
// cooperative launch is rejected. Deterministic per-machine.
// ===========================================================================
__global__ void k_pm(const float* __restrict__ emb,
                     const float* __restrict__ alphap,
                     float* __restrict__ pm) {
    const int b = blockIdx.x;
    const int j = threadIdx.x * 4;
    const float a2 = 2.0f * alphap[0];
    float4 v = *(const float4*)(emb + (size_t)b * FF * NN + 4 * NN + j);
    float4 r;
    r.x = expf(a2 * logf(v.x));
    r.y = expf(a2 * logf(v.y));
    r.z = expf(a2 * logf(v.z));
    r.w = expf(a2 * logf(v.w));
    *(float4*)(pm + b * NN + j) = r;
}

__global__ __launch_bounds__(256) void k_min(const float* __restrict__ emb,
                                             const float* __restrict__ pm,
                                             float* __restrict__ partial) {
    const int b = blockIdx.x >> 5;
    const int chunk = blockIdx.x & 31;
    const int tid = threadIdx.x, wid = tid >> 6, lane = tid & 63;
    const float* e = emb + (size_t)b * FF * NN;
    const float* pmb = pm + b * NN;

    float4 q[FF][4];
    float pj[16];
    #pragma unroll
    for (int k = 0; k < 4; ++k) {
        const int j0 = k * 256 + lane * 4;
        #pragma unroll
        for (int f = 0; f < FF; ++f) q[f][k] = *(const float4*)(e + f * NN + j0);
        float4 t = *(const float4*)(pmb + j0);
        pj[k * 4 + 0] = t.x; pj[k * 4 + 1] = t.y;
        pj[k * 4 + 2] = t.z; pj[k * 4 + 3] = t.w;
    }

    float vmin = 3.4e38f;
    for (int r = 0; r < 8; ++r) {
        const int i = chunk + 32 * (r * 4 + wid);
        const int iu = __builtin_amdgcn_readfirstlane(i);
        float eif[FF];
        #pragma unroll
        for (int f = 0; f < FF; ++f) eif[f] = e[f * NN + iu];
        const float pmi = pmb[iu];
        const int kmin = iu >> 8;
        #pragma unroll
        for (int k = 0; k < 4; ++k) {
            if (k >= kmin) {
                #pragma unroll
                for (int c = 0; c < 4; ++c) {
                    float acc = 0.0f;
                    #pragma unroll
                    for (int f = 0; f < FF; ++f) {
                        float t = ((const float*)&q[f][k])[c] - eif[f];
                        acc = fmaf(t, t, acc);
                    }
                    float dd = acc * fminf(pmi, pj[k * 4 + c]);
                    if (k == kmin) {
                        const int j = k * 256 + lane * 4 + c;
                        vmin = (j > iu) ? fminf(vmin, dd) : vmin;
                    } else {
                        vmin = fminf(vmin, dd);
                    }
                }
            }
        }
    }
    #pragma unroll
    for (int o = 32; o >= 1; o >>= 1) vmin = fminf(vmin, __shfl_xor(vmin, o));
    __shared__ float red[4];
    if (lane == 0) red[wid] = vmin;
    __syncthreads();
    if (tid == 0)
        partial[blockIdx.x] = fminf(fminf(red[0], red[1]), fminf(red[2], red[3]));
}

__global__ __launch_bounds__(256) void k_soft(const float* __restrict__ emb,
                                              const float* __restrict__ pm,
                                              const float* __restrict__ betap,
                                              const float* __restrict__ partial,
                                              float* __restrict__ out) {
    const int b = blockIdx.x >> 5;
    const int chunk = blockIdx.x & 31;
    const int tid = threadIdx.x, wid = tid >> 6, lane = tid & 63;
    const float* e = emb + (size_t)b * FF * NN;
    const float* pmb = pm + b * NN;

    __shared__ float s_dmin;
    if (tid < 32) {
        float v = partial[b * 32 + tid];
        #pragma unroll
        for (int o = 16; o >= 1; o >>= 1) v = fminf(v, __shfl_xor(v, o));
        if (tid == 0) s_dmin = v;
    }

    float4 q[FF][4];
    float pj[16];
    #pragma unroll
    for (int k = 0; k < 4; ++k) {
        const int j0 = k * 256 + lane * 4;
        #pragma unroll
        for (int f = 0; f < FF; ++f) q[f][k] = *(const float4*)(e + f * NN + j0);
        float4 t = *(const float4*)(pmb + j0);
        pj[k * 4 + 0] = t.x; pj[k * 4 + 1] = t.y;
        pj[k * 4 + 2] = t.z; pj[k * 4 + 3] = t.w;
    }
    __syncthreads();
    const float beta = betap[0];
    const float s2 = beta * beta / s_dmin * 1.4426950408889634f;

    for (int r = 0; r < 8; ++r) {
        const int i = chunk * 32 + wid * 8 + r;
        const int iu = __builtin_amdgcn_readfirstlane(i);
        float eif[FF];
        #pragma unroll
        for (int f = 0; f < FF; ++f) eif[f] = e[f * NN + iu];
        const float pmi = pmb[iu];

        float d[16];
        #pragma unroll
        for (int k = 0; k < 4; ++k)
            #pragma unroll
            for (int c = 0; c < 4; ++c) {
                float acc = 0.0f;
                #pragma unroll
                for (int f = 0; f < FF; ++f) {
                    float t = ((const float*)&q[f][k])[c] - eif[f];
                    acc = fmaf(t, t, acc);
                }
                float dd = acc * fminf(pmi, pj[k * 4 + c]);
                const int j = k * 256 + lane * 4 + c;
                d[k * 4 + c] = (j == iu) ? __builtin_inff() : dd;
            }

        float rmin = d[0];
        #pragma unroll
        for (int t = 1; t < 16; ++t) rmin = fminf(rmin, d[t]);
        #pragma unroll
        for (int o = 32; o >= 1; o >>= 1) rmin = fminf(rmin, __shfl_xor(rmin, o));

        float sum = 0.0f;
        #pragma unroll
        for (int t = 0; t < 16; ++t) {
            float p = __builtin_amdgcn_exp2f(-s2 * (d[t] - rmin));
            d[t] = p;
            sum += p;
        }
        #pragma unroll
        for (int o = 32; o >= 1; o >>= 1) sum += __shfl_xor(sum, o);
        const float inv = 1.0f / sum;

        float* op = out + ((size_t)b * NN + (size_t)i) * NN;
        #pragma unroll
        for (int k = 0; k < 4; ++k) {
            const int j0 = k * 256 + lane * 4;
            float4 w;
            w.x = d[k * 4 + 0] * inv;
            w.y = d[k * 4 + 1] * inv;
            w.z = d[k * 4 + 2] * inv;
            w.w = d[k * 4 + 3] * inv;
            *(float4*)&op[j0] = w;
        }
    }
}

extern "C" void kernel_launch(void* const* d_in, const int* in_sizes, int n_in,
                              void* d_out, int out_size, void* d_ws, size_t ws_size,
                              hipStream_t stream) {
    const float* emb   = (const float*)d_in[0];
    const float* alpha = (const float*)d_in[1];
    const float* beta  = (const float*)d_in[2];
    float* out = (float*)d_out;
    // ws layout: coop partial uses base (<=512 floats); fallback uses
    // pm = base (BB*NN floats) then partial. Only one path runs per call.
    float* wsf = (float*)d_ws;

    // Host-only queries: run only at capture/correctness time (not in replay),
    // deterministic on a given machine.
    int maxb = 0;
    hipError_t oe = hipOccupancyMaxActiveBlocksPerMultiprocessor(&maxb, k_fused, 256, 0);
    int ncu = 256, coop_attr = 1;
    {
        int dev = 0;
        if (hipGetDevice(&dev) == hipSuccess) {
            hipDeviceProp_t props;
            if (hipGetDeviceProperties(&props, dev) == hipSuccess) {
                ncu = props.multiProcessorCount;
                coop_attr = props.cooperativeLaunch;
            }
        }
    }

    if (oe == hipSuccess && coop_attr && maxb >= 1) {
        const long cap = (long)maxb * ncu;
        int bshift = 0;
        if (cap >= BB * 16 + 256) bshift = 4;        // 512 blocks, big margin
        else if (cap >= BB * 8 + 256) bshift = 3;    // 256 blocks, margin
        if (bshift) {
            float* partial = wsf;
            void* args[] = {(void*)&emb, (void*)&alpha, (void*)&beta,
                            (void*)&partial, (void*)&out, (void*)&bshift};
            hipError_t le = hipLaunchCooperativeKernel((void*)k_fused,
                                dim3(BB << bshift), dim3(256), args, 0, stream);
            if (le == hipSuccess) return;
        }
    }

    // Fallback: proven 3-kernel path.
    float* pm = wsf;
    float* partial = pm + BB * NN;
    k_pm  <<<BB,      256, 0, stream>>>(emb, alpha, pm);
    k_min <<<BB * 32, 256, 0, stream>>>(emb, pm, partial);
    k_soft<<<BB * 32, 256, 0, stream>>>(emb, pm, beta, partial, out);
}

// Round 6
// 51.294 us; speedup vs baseline: 1.0139x; 1.0139x over previous
//
#include <hip/hip_runtime.h>
#include <math.h>

#define BB 32
#define FF 6
#define NN 1024

typedef float f32x2 __attribute__((ext_vector_type(2)));

// ws layout: [0 .. BB*NN)           pm[b][j] = momentum^(2*alpha)
//            [BB*NN .. BB*NN+BB*32) per-block partial mins

// ---------------------------------------------------------------------------
// Pass 0: pm[b][j] = exp(2*alpha*log(emb[b][4][j])) — 32K precise pows, once.
// ---------------------------------------------------------------------------
__global__ void k_pm(const float* __restrict__ emb,
                     const float* __restrict__ alphap,
                     float* __restrict__ pm) {
    const int b = blockIdx.x;
    const int j = threadIdx.x * 4;
    const float a2 = 2.0f * alphap[0];
    float4 v = *(const float4*)(emb + (size_t)b * FF * NN + 4 * NN + j);
    float4 r;
    r.x = expf(a2 * logf(v.x));
    r.y = expf(a2 * logf(v.y));
    r.z = expf(a2 * logf(v.z));
    r.w = expf(a2 * logf(v.w));
    *(float4*)(pm + b * NN + j) = r;
}

// ---------------------------------------------------------------------------
// Pass 1: per-block partial min of strict-upper-triangle d_ij.
// Packed-fp32 (v_pk_*) inner loop; i is wave-uniform; kmin-balanced striding.
// ---------------------------------------------------------------------------
__global__ __launch_bounds__(256) void k_min(const float* __restrict__ emb,
                                             const float* __restrict__ pm,
                                             float* __restrict__ partial) {
    const int b = blockIdx.x >> 5;
    const int chunk = blockIdx.x & 31;
    const int tid = threadIdx.x, wid = tid >> 6, lane = tid & 63;
    const float* e = emb + (size_t)b * FF * NN;
    const float* pmb = pm + b * NN;

    // register j-tile as float2 pairs: 8 pairs x 6 features
    f32x2 q2[FF][8];
    f32x2 pj2[8];
    #pragma unroll
    for (int k = 0; k < 4; ++k) {
        const int j0 = k * 256 + lane * 4;
        #pragma unroll
        for (int f = 0; f < FF; ++f) {
            float4 v = *(const float4*)(e + f * NN + j0);
            q2[f][2 * k]     = (f32x2){v.x, v.y};
            q2[f][2 * k + 1] = (f32x2){v.z, v.w};
        }
        float4 t = *(const float4*)(pmb + j0);
        pj2[2 * k]     = (f32x2){t.x, t.y};
        pj2[2 * k + 1] = (f32x2){t.z, t.w};
    }

    f32x2 vmin2 = {3.4e38f, 3.4e38f};
    float vmin = 3.4e38f;
    for (int r = 0; r < 8; ++r) {
        const int i = chunk + 32 * (r * 4 + wid);          // wave-uniform
        const int iu = __builtin_amdgcn_readfirstlane(i);
        f32x2 ei2[FF];
        #pragma unroll
        for (int f = 0; f < FF; ++f) {
            float v = e[f * NN + iu];
            ei2[f] = (f32x2){v, v};
        }
        float pv = pmb[iu];
        f32x2 pmi2 = {pv, pv};
        const int kmin = iu >> 8;

        #pragma unroll
        for (int k = 0; k < 4; ++k) {
            if (k >= kmin) {                                // uniform branch
                #pragma unroll
                for (int h = 0; h < 2; ++h) {
                    const int p = 2 * k + h;
                    f32x2 acc = {0.0f, 0.0f};
                    #pragma unroll
                    for (int f = 0; f < FF; ++f) {
                        f32x2 t = q2[f][p] - ei2[f];        // v_pk_add neg
                        acc = __builtin_elementwise_fma(t, t, acc);  // v_pk_fma
                    }
                    f32x2 pmm = __builtin_elementwise_min(pmi2, pj2[p]);
                    f32x2 d2 = acc * pmm;                   // v_pk_mul
                    if (k == kmin) {                        // boundary: j>i test
                        const int jb = k * 256 + lane * 4 + 2 * h;
                        vmin = (jb     > iu) ? fminf(vmin, d2.x) : vmin;
                        vmin = (jb + 1 > iu) ? fminf(vmin, d2.y) : vmin;
                    } else {                                // whole pair j > i
                        vmin2 = __builtin_elementwise_min(vmin2, d2);
                    }
                }
            }
        }
    }
    vmin = fminf(vmin, fminf(vmin2.x, vmin2.y));
    #pragma unroll
    for (int o = 32; o >= 1; o >>= 1) vmin = fminf(vmin, __shfl_xor(vmin, o));
    __shared__ float red[4];
    if (lane == 0) red[wid] = vmin;
    __syncthreads();
    if (tid == 0)
        partial[blockIdx.x] = fminf(fminf(red[0], red[1]), fminf(red[2], red[3]));
}

// ---------------------------------------------------------------------------
// Pass 2: packed recompute of d, row-softmax, coalesced float4 stores.
// Diagonal = +inf -> exp2 gives exact 0 (reference: exp(<=-999) == 0).
// ---------------------------------------------------------------------------
__global__ __launch_bounds__(256) void k_soft(const float* __restrict__ emb,
                                              const float* __restrict__ pm,
                                              const float* __restrict__ betap,
                                              const float* __restrict__ partial,
                                              float* __restrict__ out) {
    const int b = blockIdx.x >> 5;
    const int chunk = blockIdx.x & 31;
    const int tid = threadIdx.x, wid = tid >> 6, lane = tid & 63;
    const float* e = emb + (size_t)b * FF * NN;
    const float* pmb = pm + b * NN;

    __shared__ float s_dmin;
    if (tid < 32) {
        float v = partial[b * 32 + tid];
        #pragma unroll
        for (int o = 16; o >= 1; o >>= 1) v = fminf(v, __shfl_xor(v, o));
        if (tid == 0) s_dmin = v;
    }

    f32x2 q2[FF][8];
    f32x2 pj2[8];
    #pragma unroll
    for (int k = 0; k < 4; ++k) {
        const int j0 = k * 256 + lane * 4;
        #pragma unroll
        for (int f = 0; f < FF; ++f) {
            float4 v = *(const float4*)(e + f * NN + j0);
            q2[f][2 * k]     = (f32x2){v.x, v.y};
            q2[f][2 * k + 1] = (f32x2){v.z, v.w};
        }
        float4 t = *(const float4*)(pmb + j0);
        pj2[2 * k]     = (f32x2){t.x, t.y};
        pj2[2 * k + 1] = (f32x2){t.z, t.w};
    }
    __syncthreads();
    const float beta = betap[0];
    const float s2 = beta * beta / s_dmin * 1.4426950408889634f;  // log2e folded
    const f32x2 s2v = {s2, s2};

    for (int r = 0; r < 8; ++r) {
        const int i = chunk * 32 + wid * 8 + r;             // wave-uniform
        const int iu = __builtin_amdgcn_readfirstlane(i);
        f32x2 ei2[FF];
        #pragma unroll
        for (int f = 0; f < FF; ++f) {
            float v = e[f * NN + iu];
            ei2[f] = (f32x2){v, v};
        }
        float pv = pmb[iu];
        f32x2 pmi2 = {pv, pv};
        const int km = iu >> 8;
        const int lane4 = lane * 4;

        f32x2 d2[8];
        #pragma unroll
        for (int k = 0; k < 4; ++k) {
            #pragma unroll
            for (int h = 0; h < 2; ++h) {
                const int p = 2 * k + h;
                f32x2 acc = {0.0f, 0.0f};
                #pragma unroll
                for (int f = 0; f < FF; ++f) {
                    f32x2 t = q2[f][p] - ei2[f];
                    acc = __builtin_elementwise_fma(t, t, acc);
                }
                f32x2 pmm = __builtin_elementwise_min(pmi2, pj2[p]);
                f32x2 dd = acc * pmm;
                if (k == km) {                              // uniform branch
                    const int jb = k * 256 + lane4 + 2 * h;
                    if (jb == iu)     dd.x = __builtin_inff();
                    if (jb + 1 == iu) dd.y = __builtin_inff();
                }
                d2[p] = dd;
            }
        }

        // row min (softmax shift); +inf diag never wins
        f32x2 rm2 = d2[0];
        #pragma unroll
        for (int p = 1; p < 8; ++p) rm2 = __builtin_elementwise_min(rm2, d2[p]);
        float rmin = fminf(rm2.x, rm2.y);
        #pragma unroll
        for (int o = 32; o >= 1; o >>= 1) rmin = fminf(rmin, __shfl_xor(rmin, o));
        const f32x2 rminv = {rmin, rmin};

        f32x2 sum2 = {0.0f, 0.0f};
        #pragma unroll
        for (int p = 0; p < 8; ++p) {
            f32x2 a = (rminv - d2[p]) * s2v;                // pk_add(neg) + pk_mul
            f32x2 pe;
            pe.x = __builtin_amdgcn_exp2f(a.x);             // diag -> exp2(-inf)=0
            pe.y = __builtin_amdgcn_exp2f(a.y);
            d2[p] = pe;
            sum2 += pe;                                     // pk_add
        }
        float sum = sum2.x + sum2.y;
        #pragma unroll
        for (int o = 32; o >= 1; o >>= 1) sum += __shfl_xor(sum, o);
        const float inv = 1.0f / sum;
        const f32x2 invv = {inv, inv};

        float* op = out + ((size_t)b * NN + (size_t)iu) * NN;
        #pragma unroll
        for (int k = 0; k < 4; ++k) {
            f32x2 r0 = d2[2 * k] * invv;                    // pk_mul
            f32x2 r1 = d2[2 * k + 1] * invv;
            float4 w;
            w.x = r0.x; w.y = r0.y; w.z = r1.x; w.w = r1.y;
            *(float4*)&op[k * 256 + lane4] = w;
        }
    }
}

extern "C" void kernel_launch(void* const* d_in, const int* in_sizes, int n_in,
                              void* d_out, int out_size, void* d_ws, size_t ws_size,
                              hipStream_t stream) {
    const float* emb   = (const float*)d_in[0];
    const float* alpha = (const float*)d_in[1];
    const float* beta  = (const float*)d_in[2];
    float* out = (float*)d_out;
    float* pm = (float*)d_ws;             // BB*NN floats
    float* partial = pm + BB * NN;        // BB*32 floats

    k_pm  <<<BB,      256, 0, stream>>>(emb, alpha, pm);
    k_min <<<BB * 32, 256, 0, stream>>>(emb, pm, partial);
    k_soft<<<BB * 32, 256, 0, stream>>>(emb, pm, beta, partial, out);
}

// Round 7
// 42.906 us; speedup vs baseline: 1.2122x; 1.1955x over previous
//
#include <hip/hip_runtime.h>
#include <math.h>

#define BB 32
#define FF 6
#define NN 1024

// ws layout: [0 .. BB*32) per-block partial mins (4 KB)

// ---------------------------------------------------------------------------
// Pass 1: per-block partial min of strict-upper-triangle d_ij.
// j-tile (6 features + pm) lives in LDS (28 KB); each 256-col chunk is read
// ONCE per 4-row group (7 ds_read_b128) and reused 16x -> LDS traffic ~56B/row
// instead of 448B/row of L2 re-reads (the round-1..6 bottleneck).
// Rows per wave: i = chunk + 32*wid + 128*r (kmin-balanced).
// ---------------------------------------------------------------------------
__global__ __launch_bounds__(256) void k_min(const float* __restrict__ emb,
                                             const float* __restrict__ alphap,
                                             float* __restrict__ partial) {
    __shared__ float s_tile[7][NN];   // rows 0..5 = features, row 6 = pm
    __shared__ float red[4];
    const int b = blockIdx.x >> 5, chunk = blockIdx.x & 31;
    const int tid = threadIdx.x, wid = tid >> 6, lane = tid & 63;
    const float* e = emb + (size_t)b * FF * NN;

    #pragma unroll
    for (int t = 0; t < 6; ++t) {                       // stage 6 feature rows
        const int idx = t * 256 + tid;
        const int f = idx >> 8, j4 = idx & 255;
        ((float4*)&s_tile[f][0])[j4] = ((const float4*)(e + (size_t)f * NN))[j4];
    }
    {                                                   // pm = mom^(2*alpha)
        const float a2 = 2.0f * alphap[0];
        float4 m = *(const float4*)(e + 4 * NN + 4 * tid);
        float4 r;
        r.x = expf(a2 * logf(m.x));
        r.y = expf(a2 * logf(m.y));
        r.z = expf(a2 * logf(m.z));
        r.w = expf(a2 * logf(m.w));
        *(float4*)&s_tile[6][4 * tid] = r;
    }
    __syncthreads();

    float vmin = 3.4e38f;
    #pragma unroll
    for (int g = 0; g < 2; ++g) {
        int ii[4];
        float ei[4][FF], pmi[4];
        #pragma unroll
        for (int rr = 0; rr < 4; ++rr) {                // row scalars: broadcast
            ii[rr] = chunk + 32 * wid + 128 * (g * 4 + rr);
            #pragma unroll
            for (int f = 0; f < FF; ++f) ei[rr][f] = s_tile[f][ii[rr]];
            pmi[rr] = s_tile[6][ii[rr]];
        }
        #pragma unroll
        for (int k = 0; k < 4; ++k) {
            if (k >= (ii[0] >> 8)) {                    // wave-uniform chunk skip
                float4 q[FF], pk4;
                #pragma unroll
                for (int f = 0; f < FF; ++f)
                    q[f] = ((const float4*)&s_tile[f][k * 256])[lane];
                pk4 = ((const float4*)&s_tile[6][k * 256])[lane];
                #pragma unroll
                for (int rr = 0; rr < 4; ++rr) {
                    const int i = ii[rr], km = i >> 8;
                    if (k > km) {                       // whole chunk is j > i
                        #pragma unroll
                        for (int c = 0; c < 4; ++c) {
                            float acc = 0.0f;
                            #pragma unroll
                            for (int f = 0; f < FF; ++f) {
                                float t = ((const float*)&q[f])[c] - ei[rr][f];
                                acc = fmaf(t, t, acc);  // no-cancellation form
                            }
                            vmin = fminf(vmin,
                                acc * fminf(pmi[rr], ((const float*)&pk4)[c]));
                        }
                    } else if (k == km) {               // boundary chunk: j>i test
                        #pragma unroll
                        for (int c = 0; c < 4; ++c) {
                            float acc = 0.0f;
                            #pragma unroll
                            for (int f = 0; f < FF; ++f) {
                                float t = ((const float*)&q[f])[c] - ei[rr][f];
                                acc = fmaf(t, t, acc);
                            }
                            float dd = acc * fminf(pmi[rr], ((const float*)&pk4)[c]);
                            const int j = k * 256 + lane * 4 + c;
                            vmin = (j > i) ? fminf(vmin, dd) : vmin;
                        }
                    }
                }
            }
        }
    }
    #pragma unroll
    for (int o = 32; o >= 1; o >>= 1) vmin = fminf(vmin, __shfl_xor(vmin, o));
    if (lane == 0) red[wid] = vmin;
    __syncthreads();
    if (tid == 0)
        partial[blockIdx.x] = fminf(fminf(red[0], red[1]), fminf(red[2], red[3]));
}

// ---------------------------------------------------------------------------
// Pass 2: same LDS-tile + 4-row-group structure; pm pre-scaled by s2 so the
// exponent is a single subtract; row-softmax; coalesced float4 stores.
// Diagonal = +inf -> exp2 gives exact 0 (reference: exp(<=-999) == 0).
// ---------------------------------------------------------------------------
__global__ __launch_bounds__(256) void k_soft(const float* __restrict__ emb,
                                              const float* __restrict__ alphap,
                                              const float* __restrict__ betap,
                                              const float* __restrict__ partial,
                                              float* __restrict__ out) {
    __shared__ float s_tile[7][NN];
    __shared__ float s_dmin;
    const int b = blockIdx.x >> 5, chunk = blockIdx.x & 31;
    const int tid = threadIdx.x, wid = tid >> 6, lane = tid & 63;
    const float* e = emb + (size_t)b * FF * NN;

    if (tid < 32) {                                     // batch dmin
        float v = partial[b * 32 + tid];
        #pragma unroll
        for (int o = 16; o >= 1; o >>= 1) v = fminf(v, __shfl_xor(v, o));
        if (tid == 0) s_dmin = v;
    }
    #pragma unroll
    for (int t = 0; t < 6; ++t) {
        const int idx = t * 256 + tid;
        const int f = idx >> 8, j4 = idx & 255;
        ((float4*)&s_tile[f][0])[j4] = ((const float4*)(e + (size_t)f * NN))[j4];
    }
    __syncthreads();                                    // s_dmin + features ready
    const float beta = betap[0];
    const float s2 = beta * beta / s_dmin * 1.4426950408889634f;  // log2e folded
    {                                                   // pm pre-scaled by s2
        const float a2 = 2.0f * alphap[0];
        float4 m = *(const float4*)(e + 4 * NN + 4 * tid);
        float4 r;
        r.x = s2 * expf(a2 * logf(m.x));
        r.y = s2 * expf(a2 * logf(m.y));
        r.z = s2 * expf(a2 * logf(m.z));
        r.w = s2 * expf(a2 * logf(m.w));
        *(float4*)&s_tile[6][4 * tid] = r;
    }
    __syncthreads();

    const int kd = chunk >> 3;                          // diag chunk (block-uniform)
    #pragma unroll
    for (int g = 0; g < 2; ++g) {
        int ii[4];
        float ei[4][FF], pmi[4];
        #pragma unroll
        for (int rr = 0; rr < 4; ++rr) {
            ii[rr] = chunk * 32 + wid * 8 + g * 4 + rr;
            #pragma unroll
            for (int f = 0; f < FF; ++f) ei[rr][f] = s_tile[f][ii[rr]];
            pmi[rr] = s_tile[6][ii[rr]];                // s2-scaled
        }
        float d[4][16];
        #pragma unroll
        for (int k = 0; k < 4; ++k) {
            float4 q[FF], pk4;
            #pragma unroll
            for (int f = 0; f < FF; ++f)
                q[f] = ((const float4*)&s_tile[f][k * 256])[lane];
            pk4 = ((const float4*)&s_tile[6][k * 256])[lane];
            #pragma unroll
            for (int rr = 0; rr < 4; ++rr) {
                #pragma unroll
                for (int c = 0; c < 4; ++c) {
                    float acc = 0.0f;
                    #pragma unroll
                    for (int f = 0; f < FF; ++f) {
                        float t = ((const float*)&q[f])[c] - ei[rr][f];
                        acc = fmaf(t, t, acc);
                    }
                    d[rr][k * 4 + c] =
                        acc * fminf(pmi[rr], ((const float*)&pk4)[c]);  // = s2*d
                }
            }
            if (k == kd) {                              // diagonal fixup
                #pragma unroll
                for (int rr = 0; rr < 4; ++rr) {
                    #pragma unroll
                    for (int c = 0; c < 4; ++c)
                        if (k * 256 + lane * 4 + c == ii[rr])
                            d[rr][k * 4 + c] = __builtin_inff();
                }
            }
        }
        #pragma unroll
        for (int rr = 0; rr < 4; ++rr) {
            float rmin = fminf(d[rr][0], d[rr][1]);
            #pragma unroll
            for (int t = 2; t < 16; ++t) rmin = fminf(rmin, d[rr][t]);
            #pragma unroll
            for (int o = 32; o >= 1; o >>= 1)
                rmin = fminf(rmin, __shfl_xor(rmin, o));

            float sum = 0.0f;
            #pragma unroll
            for (int t = 0; t < 16; ++t) {
                float p = __builtin_amdgcn_exp2f(rmin - d[rr][t]);  // diag -> 0
                d[rr][t] = p;
                sum += p;
            }
            #pragma unroll
            for (int o = 32; o >= 1; o >>= 1) sum += __shfl_xor(sum, o);
            const float inv = 1.0f / sum;

            float* op = out + ((size_t)b * NN + (size_t)ii[rr]) * NN;
            #pragma unroll
            for (int k = 0; k < 4; ++k) {
                float4 w;
                w.x = d[rr][k * 4 + 0] * inv;
                w.y = d[rr][k * 4 + 1] * inv;
                w.z = d[rr][k * 4 + 2] * inv;
                w.w = d[rr][k * 4 + 3] * inv;
                *(float4*)&op[k * 256 + lane * 4] = w;
            }
        }
    }
}

extern "C" void kernel_launch(void* const* d_in, const int* in_sizes, int n_in,
                              void* d_out, int out_size, void* d_ws, size_t ws_size,
                              hipStream_t stream) {
    const float* emb   = (const float*)d_in[0];
    const float* alpha = (const float*)d_in[1];
    const float* beta  = (const float*)d_in[2];
    float* out = (float*)d_out;
    float* partial = (float*)d_ws;   // BB*32 floats, fully rewritten every call

    k_min <<<BB * 32, 256, 0, stream>>>(emb, alpha, partial);
    k_soft<<<BB * 32, 256, 0, stream>>>(emb, alpha, beta, partial, out);
}

// Round 9
// 39.376 us; speedup vs baseline: 1.3208x; 1.0896x over previous
//
#include <hip/hip_runtime.h>
#include <math.h>

#define BB 32
#define FF 6
#define NN 1024

typedef float f4 __attribute__((ext_vector_type(4)));

// ---- DPP wave-64 reductions (VALU-only, no LDS pipe) -----------------------
// ctrl/rmask must be literal constants -> template parameters.
template <int CTRL, int RMASK>
__device__ __forceinline__ float dpp_f(float v, float old) {
    return __builtin_bit_cast(float,
        __builtin_amdgcn_update_dpp(__builtin_bit_cast(int, old),
                                    __builtin_bit_cast(int, v),
                                    CTRL, RMASK, 0xF, false));
}
__device__ __forceinline__ float wave_min64(float v) {
    const float I = __builtin_inff();
    v = fminf(v, dpp_f<0x111, 0xF>(v, I));   // row_shr:1
    v = fminf(v, dpp_f<0x112, 0xF>(v, I));   // row_shr:2
    v = fminf(v, dpp_f<0x114, 0xF>(v, I));   // row_shr:4
    v = fminf(v, dpp_f<0x118, 0xF>(v, I));   // row_shr:8
    v = fminf(v, dpp_f<0x142, 0xA>(v, I));   // row_bcast:15 -> rows 1,3
    v = fminf(v, dpp_f<0x143, 0xC>(v, I));   // row_bcast:31 -> rows 2,3
    return __builtin_bit_cast(float,
        __builtin_amdgcn_readlane(__builtin_bit_cast(int, v), 63));
}
__device__ __forceinline__ float wave_sum64(float v) {
    v += dpp_f<0x111, 0xF>(v, 0.0f);
    v += dpp_f<0x112, 0xF>(v, 0.0f);
    v += dpp_f<0x114, 0xF>(v, 0.0f);
    v += dpp_f<0x118, 0xF>(v, 0.0f);
    v += dpp_f<0x142, 0xA>(v, 0.0f);
    v += dpp_f<0x143, 0xC>(v, 0.0f);
    return __builtin_bit_cast(float,
        __builtin_amdgcn_readlane(__builtin_bit_cast(int, v), 63));
}

__device__ __forceinline__ float4 pm4(float4 m, float a2) {
    float4 r;
    if (a2 == 2.0f) {            // dataset fast path: alpha == 1 -> pm = m*m
        r.x = m.x * m.x; r.y = m.y * m.y; r.z = m.z * m.z; r.w = m.w * m.w;
    } else {
        r.x = expf(a2 * logf(m.x));
        r.y = expf(a2 * logf(m.y));
        r.z = expf(a2 * logf(m.z));
        r.w = expf(a2 * logf(m.w));
    }
    return r;
}

// ---------------------------------------------------------------------------
// Pass 1: per-block partial min of strict-upper-triangle d_ij.
// LDS tile (6 features + pm, 28 KB); each 256-col chunk read once per
// 4-row group and reused 16x. Rows: i = chunk + 32*wid + 128*r (balanced).
// ---------------------------------------------------------------------------
__global__ __launch_bounds__(256) void k_min(const float* __restrict__ emb,
                                             const float* __restrict__ alphap,
                                             float* __restrict__ partial) {
    __shared__ float s_tile[7][NN];
    __shared__ float red[4];
    const int b = blockIdx.x >> 5, chunk = blockIdx.x & 31;
    const int tid = threadIdx.x, wid = tid >> 6, lane = tid & 63;
    const float* e = emb + (size_t)b * FF * NN;

    #pragma unroll
    for (int t = 0; t < 6; ++t) {
        const int idx = t * 256 + tid;
        const int f = idx >> 8, j4 = idx & 255;
        ((float4*)&s_tile[f][0])[j4] = ((const float4*)(e + (size_t)f * NN))[j4];
    }
    {
        const float a2 = 2.0f * alphap[0];
        float4 m = *(const float4*)(e + 4 * NN + 4 * tid);
        *(float4*)&s_tile[6][4 * tid] = pm4(m, a2);
    }
    __syncthreads();

    float vmin = 3.4e38f;
    #pragma unroll
    for (int g = 0; g < 2; ++g) {
        int ii[4];
        float ei[4][FF], pmi[4];
        #pragma unroll
        for (int rr = 0; rr < 4; ++rr) {
            ii[rr] = chunk + 32 * wid + 128 * (g * 4 + rr);
            #pragma unroll
            for (int f = 0; f < FF; ++f) ei[rr][f] = s_tile[f][ii[rr]];
            pmi[rr] = s_tile[6][ii[rr]];
        }
        #pragma unroll
        for (int k = 0; k < 4; ++k) {
            if (k >= (ii[0] >> 8)) {                    // wave-uniform skip
                float4 q[FF], pk4;
                #pragma unroll
                for (int f = 0; f < FF; ++f)
                    q[f] = ((const float4*)&s_tile[f][k * 256])[lane];
                pk4 = ((const float4*)&s_tile[6][k * 256])[lane];
                #pragma unroll
                for (int rr = 0; rr < 4; ++rr) {
                    const int i = ii[rr], km = i >> 8;
                    if (k > km) {
                        #pragma unroll
                        for (int c = 0; c < 4; ++c) {
                            float acc = 0.0f;
                            #pragma unroll
                            for (int f = 0; f < FF; ++f) {
                                float t = ((const float*)&q[f])[c] - ei[rr][f];
                                acc = fmaf(t, t, acc);  // no-cancellation form
                            }
                            vmin = fminf(vmin,
                                acc * fminf(pmi[rr], ((const float*)&pk4)[c]));
                        }
                    } else if (k == km) {
                        #pragma unroll
                        for (int c = 0; c < 4; ++c) {
                            float acc = 0.0f;
                            #pragma unroll
                            for (int f = 0; f < FF; ++f) {
                                float t = ((const float*)&q[f])[c] - ei[rr][f];
                                acc = fmaf(t, t, acc);
                            }
                            float dd = acc * fminf(pmi[rr], ((const float*)&pk4)[c]);
                            const int j = k * 256 + lane * 4 + c;
                            vmin = (j > i) ? fminf(vmin, dd) : vmin;
                        }
                    }
                }
            }
        }
    }
    vmin = wave_min64(vmin);
    if (lane == 0) red[wid] = vmin;
    __syncthreads();
    if (tid == 0)
        partial[blockIdx.x] = fminf(fminf(red[0], red[1]), fminf(red[2], red[3]));
}

// ---------------------------------------------------------------------------
// Pass 2: LDS tile + 4-row-group recompute; pm pre-scaled by s2; DPP-reduced
// row softmax; nontemporal float4 stores (write-once output).
// Diagonal = +inf -> exp2 gives exact 0 (reference: exp(<=-999) == 0).
// ---------------------------------------------------------------------------
__global__ __launch_bounds__(256) void k_soft(const float* __restrict__ emb,
                                              const float* __restrict__ alphap,
                                              const float* __restrict__ betap,
                                              const float* __restrict__ partial,
                                              float* __restrict__ out) {
    __shared__ float s_tile[7][NN];
    __shared__ float s_dmin;
    const int b = blockIdx.x >> 5, chunk = blockIdx.x & 31;
    const int tid = threadIdx.x, wid = tid >> 6, lane = tid & 63;
    const float* e = emb + (size_t)b * FF * NN;

    if (tid < 32) {
        float v = partial[b * 32 + tid];
        #pragma unroll
        for (int o = 16; o >= 1; o >>= 1) v = fminf(v, __shfl_xor(v, o));
        if (tid == 0) s_dmin = v;
    }
    #pragma unroll
    for (int t = 0; t < 6; ++t) {
        const int idx = t * 256 + tid;
        const int f = idx >> 8, j4 = idx & 255;
        ((float4*)&s_tile[f][0])[j4] = ((const float4*)(e + (size_t)f * NN))[j4];
    }
    __syncthreads();
    const float beta = betap[0];
    const float s2 = beta * beta / s_dmin * 1.4426950408889634f;
    {
        const float a2 = 2.0f * alphap[0];
        float4 m = *(const float4*)(e + 4 * NN + 4 * tid);
        float4 r = pm4(m, a2);
        r.x *= s2; r.y *= s2; r.z *= s2; r.w *= s2;   // pre-scale by s2
        *(float4*)&s_tile[6][4 * tid] = r;
    }
    __syncthreads();

    const int kd = chunk >> 3;                        // diagonal chunk
    #pragma unroll
    for (int g = 0; g < 2; ++g) {
        int ii[4];
        float ei[4][FF], pmi[4];
        #pragma unroll
        for (int rr = 0; rr < 4; ++rr) {
            ii[rr] = chunk * 32 + wid * 8 + g * 4 + rr;
            #pragma unroll
            for (int f = 0; f < FF; ++f) ei[rr][f] = s_tile[f][ii[rr]];
            pmi[rr] = s_tile[6][ii[rr]];
        }
        float d[4][16];
        #pragma unroll
        for (int k = 0; k < 4; ++k) {
            float4 q[FF], pk4;
            #pragma unroll
            for (int f = 0; f < FF; ++f)
                q[f] = ((const float4*)&s_tile[f][k * 256])[lane];
            pk4 = ((const float4*)&s_tile[6][k * 256])[lane];
            #pragma unroll
            for (int rr = 0; rr < 4; ++rr) {
                #pragma unroll
                for (int c = 0; c < 4; ++c) {
                    float acc = 0.0f;
                    #pragma unroll
                    for (int f = 0; f < FF; ++f) {
                        float t = ((const float*)&q[f])[c] - ei[rr][f];
                        acc = fmaf(t, t, acc);
                    }
                    d[rr][k * 4 + c] =
                        acc * fminf(pmi[rr], ((const float*)&pk4)[c]);
                }
            }
            if (k == kd) {
                #pragma unroll
                for (int rr = 0; rr < 4; ++rr) {
                    #pragma unroll
                    for (int c = 0; c < 4; ++c)
                        if (k * 256 + lane * 4 + c == ii[rr])
                            d[rr][k * 4 + c] = __builtin_inff();
                }
            }
        }
        #pragma unroll
        for (int rr = 0; rr < 4; ++rr) {
            float rmin = fminf(d[rr][0], d[rr][1]);
            #pragma unroll
            for (int t = 2; t < 16; ++t) rmin = fminf(rmin, d[rr][t]);
            rmin = wave_min64(rmin);                  // DPP, VALU-only

            float sum = 0.0f;
            #pragma unroll
            for (int t = 0; t < 16; ++t) {
                float p = __builtin_amdgcn_exp2f(rmin - d[rr][t]);  // diag -> 0
                d[rr][t] = p;
                sum += p;
            }
            sum = wave_sum64(sum);                    // DPP, VALU-only
            const float inv = 1.0f / sum;

            float* op = out + ((size_t)b * NN + (size_t)ii[rr]) * NN;
            #pragma unroll
            for (int k = 0; k < 4; ++k) {
                f4 w;
                w.x = d[rr][k * 4 + 0] * inv;
                w.y = d[rr][k * 4 + 1] * inv;
                w.z = d[rr][k * 4 + 2] * inv;
                w.w = d[rr][k * 4 + 3] * inv;
                __builtin_nontemporal_store(w, (f4*)&op[k * 256 + lane * 4]);
            }
        }
    }
}

extern "C" void kernel_launch(void* const* d_in, const int* in_sizes, int n_in,
                              void* d_out, int out_size, void* d_ws, size_t ws_size,
                              hipStream_t stream) {
    const float* emb   = (const float*)d_in[0];
    const float* alpha = (const float*)d_in[1];
    const float* beta  = (const float*)d_in[2];
    float* out = (float*)d_out;
    float* partial = (float*)d_ws;   // BB*32 floats, fully rewritten every call

    k_min <<<BB * 32, 256, 0, stream>>>(emb, alpha, partial);
    k_soft<<<BB * 32, 256, 0, stream>>>(emb, alpha, beta, partial, out);
}